// Round 1
// baseline (386.079 us; speedup 1.0000x reference)
//
#include <hip/hip_runtime.h>
#include <hip/hip_bf16.h>

#define S 9216      // 96*96 spatial positions
#define C 256       // channels
#define NT 72       // 9216 / 128 tiles per dim

typedef __bf16 bf16x8 __attribute__((ext_vector_type(8)));
typedef float f32x4 __attribute__((ext_vector_type(4)));

#define GLOAD_LDS16(g, l) __builtin_amdgcn_global_load_lds( \
    (const __attribute__((address_space(1))) void*)(g),     \
    (__attribute__((address_space(3))) void*)(l), 16, 0, 0)

// ---------------- mean of gt over spatial, per channel ----------------
__global__ __launch_bounds__(256) void k_mean(const float* __restrict__ gt,
                                              float* __restrict__ meanT) {
    const int c = blockIdx.x;
    const float* p = gt + (size_t)c * S;
    float s = 0.f;
    for (int i = threadIdx.x; i < S; i += 256) s += p[i];
    for (int m = 1; m < 64; m <<= 1) s += __shfl_xor(s, m, 64);
    __shared__ float red[4];
    if ((threadIdx.x & 63) == 0) red[threadIdx.x >> 6] = s;
    __syncthreads();
    if (threadIdx.x == 0)
        meanT[c] = (red[0] + red[1] + red[2] + red[3]) * (1.0f / S);
}

// ------- center by mean_t, L2-normalize over C, transpose to [S][C] bf16 -------
// 4 lanes per spatial position, 64 channels each.
__global__ __launch_bounds__(256) void k_norm(const float* __restrict__ img,
                                              const float* __restrict__ gt,
                                              const float* __restrict__ meanT,
                                              __hip_bfloat16* __restrict__ A,
                                              __hip_bfloat16* __restrict__ B) {
    __shared__ float sm[C];
    if (threadIdx.x < C) sm[threadIdx.x] = meanT[threadIdx.x];
    __syncthreads();
    const int gtid = blockIdx.x * 256 + threadIdx.x;
    const int s    = gtid >> 2;          // spatial position
    const int part = gtid & 3;           // channel quarter
    const int c0   = part * 64;
    float si = 0.f, st = 0.f;
    for (int k = 0; k < 64; ++k) {
        const int c = c0 + k;
        const float m  = sm[c];
        const float di = img[(size_t)c * S + s] - m;
        const float dt = gt [(size_t)c * S + s] - m;
        si += di * di;
        st += dt * dt;
    }
    // combine the 4 lanes covering this position (xor 1,2 stays in the group)
    si += __shfl_xor(si, 1, 64); si += __shfl_xor(si, 2, 64);
    st += __shfl_xor(st, 1, 64); st += __shfl_xor(st, 2, 64);
    const float ri = 1.0f / fmaxf(sqrtf(si), 1e-12f);
    const float rt = 1.0f / fmaxf(sqrtf(st), 1e-12f);
    for (int k = 0; k < 64; ++k) {
        const int c = c0 + k;
        const float m = sm[c];
        A[(size_t)s * C + c] = __float2bfloat16((img[(size_t)c * S + s] - m) * ri);
        B[(size_t)s * C + c] = __float2bfloat16((gt [(size_t)c * S + s] - m) * rt);
    }
}

// ---------------- init reduction buffers ----------------
__global__ __launch_bounds__(256) void k_init(float* __restrict__ rowmin,
                                              float* __restrict__ rowsum,
                                              float* __restrict__ colmax) {
    const int i = blockIdx.x * 256 + threadIdx.x;
    if (i < S) {
        rowmin[i] = __uint_as_float(0x7f800000u);  // +inf
        rowsum[i] = 0.f;
        colmax[i] = 0.f;
    }
}

// ---------------- fused GEMM passes ----------------
// dot[r,s] = sum_c A[r,c]*B[s,c]; raw = max((1-dot)/2, 0)
// PASS 1: rowmin[r] = min_s raw            (atomicMin on uint bits, raw>=0)
// PASS 2: rowsum[r] = sum_s exp(2(1-raw/(rowmin+eps)))
// PASS 3: colmax[s] = max_r w/rowsum[r]    (atomicMax on uint bits)
template<int PASS>
__global__ __launch_bounds__(256) void k_gemm(const __hip_bfloat16* __restrict__ A,
                                              const __hip_bfloat16* __restrict__ B,
                                              float* __restrict__ rowmin,
                                              float* __restrict__ rowsum,
                                              float* __restrict__ colmax) {
    __shared__ alignas(16) __hip_bfloat16 As[128 * 32];
    __shared__ alignas(16) __hip_bfloat16 Bs[128 * 32];
    const int tid  = threadIdx.x;
    const int lane = tid & 63;
    const int wid  = tid >> 6;
    const int wr   = wid >> 1;      // wave row (0..1), 64 rows each
    const int wc   = wid & 1;       // wave col (0..1), 64 cols each
    const int rowBase = blockIdx.y * 128;
    const int colBase = blockIdx.x * 128;

    const int frow = lane & 15;     // A-row / B-col within 16x16 frag
    const int kgrp = lane >> 4;     // k-group: elements kgrp*8 .. +8

    f32x4 acc[4][4] = {};

    const int rsub = lane >> 2;           // 0..15 row within 16-row chunk
    const int csub = (lane & 3) * 8;      // element offset within 32-elem row

    for (int kt = 0; kt < C / 32; ++kt) {
        // ---- stage A,B tiles: each wave fills its 32 rows (2 x 16-row chunks)
        for (int i = 0; i < 2; ++i) {
            const int r0 = wid * 32 + i * 16;
            const __hip_bfloat16* ga = A + (size_t)(rowBase + r0 + rsub) * C + kt * 32 + csub;
            const __hip_bfloat16* gb = B + (size_t)(colBase + r0 + rsub) * C + kt * 32 + csub;
            GLOAD_LDS16(ga, &As[r0 * 32]);
            GLOAD_LDS16(gb, &Bs[r0 * 32]);
        }
        __syncthreads();

        bf16x8 af[4], bfr[4];
        for (int m = 0; m < 4; ++m)
            af[m] = *reinterpret_cast<const bf16x8*>(&As[(wr * 64 + m * 16 + frow) * 32 + kgrp * 8]);
        for (int n = 0; n < 4; ++n)
            bfr[n] = *reinterpret_cast<const bf16x8*>(&Bs[(wc * 64 + n * 16 + frow) * 32 + kgrp * 8]);
        for (int m = 0; m < 4; ++m)
            for (int n = 0; n < 4; ++n)
                acc[m][n] = __builtin_amdgcn_mfma_f32_16x16x32_bf16(af[m], bfr[n], acc[m][n], 0, 0, 0);
        __syncthreads();
    }

    // ---- epilogue: C/D mapping: col = lane&15, row = (lane>>4)*4 + q [m89]
    if (PASS == 1) {
        for (int m = 0; m < 4; ++m)
            for (int q = 0; q < 4; ++q) {
                float v = 1e30f;
                for (int n = 0; n < 4; ++n) {
                    const float raw = fmaxf(0.5f * (1.0f - acc[m][n][q]), 0.0f);
                    v = fminf(v, raw);
                }
                v = fminf(v, __shfl_xor(v, 1, 64));
                v = fminf(v, __shfl_xor(v, 2, 64));
                v = fminf(v, __shfl_xor(v, 4, 64));
                v = fminf(v, __shfl_xor(v, 8, 64));
                if (frow == 0) {
                    const int rg = rowBase + wr * 64 + m * 16 + kgrp * 4 + q;
                    atomicMin((unsigned int*)&rowmin[rg], __float_as_uint(v));
                }
            }
    } else if (PASS == 2) {
        for (int m = 0; m < 4; ++m)
            for (int q = 0; q < 4; ++q) {
                const int rg = rowBase + wr * 64 + m * 16 + kgrp * 4 + q;
                const float inv = 1.0f / (rowmin[rg] + 1e-5f);
                float sum = 0.f;
                for (int n = 0; n < 4; ++n) {
                    const float raw = fmaxf(0.5f * (1.0f - acc[m][n][q]), 0.0f);
                    sum += __expf(2.0f * (1.0f - raw * inv));
                }
                sum += __shfl_xor(sum, 1, 64);
                sum += __shfl_xor(sum, 2, 64);
                sum += __shfl_xor(sum, 4, 64);
                sum += __shfl_xor(sum, 8, 64);
                if (frow == 0) atomicAdd(&rowsum[rg], sum);
            }
    } else {
        float cmax[4] = {0.f, 0.f, 0.f, 0.f};
        for (int m = 0; m < 4; ++m)
            for (int q = 0; q < 4; ++q) {
                const int rg = rowBase + wr * 64 + m * 16 + kgrp * 4 + q;
                const float inv = 1.0f / (rowmin[rg] + 1e-5f);
                const float rs  = 1.0f / rowsum[rg];
                for (int n = 0; n < 4; ++n) {
                    const float raw = fmaxf(0.5f * (1.0f - acc[m][n][q]), 0.0f);
                    const float cx  = __expf(2.0f * (1.0f - raw * inv)) * rs;
                    cmax[n] = fmaxf(cmax[n], cx);
                }
            }
        for (int n = 0; n < 4; ++n) {
            float v = cmax[n];
            v = fmaxf(v, __shfl_xor(v, 16, 64));
            v = fmaxf(v, __shfl_xor(v, 32, 64));
            if (kgrp == 0) {
                const int cg = colBase + wc * 64 + n * 16 + frow;
                atomicMax((unsigned int*)&colmax[cg], __float_as_uint(v));
            }
        }
    }
}

// ---------------- final: loss = -log(mean_s colmax[s]) ----------------
__global__ __launch_bounds__(256) void k_final(const float* __restrict__ colmax,
                                               float* __restrict__ out) {
    float s = 0.f;
    for (int i = threadIdx.x; i < S; i += 256) s += colmax[i];
    for (int m = 1; m < 64; m <<= 1) s += __shfl_xor(s, m, 64);
    __shared__ float red[4];
    if ((threadIdx.x & 63) == 0) red[threadIdx.x >> 6] = s;
    __syncthreads();
    if (threadIdx.x == 0)
        out[0] = -logf((red[0] + red[1] + red[2] + red[3]) * (1.0f / S));
}

extern "C" void kernel_launch(void* const* d_in, const int* in_sizes, int n_in,
                              void* d_out, int out_size, void* d_ws, size_t ws_size,
                              hipStream_t stream) {
    const float* img = (const float*)d_in[0];
    const float* gt  = (const float*)d_in[1];

    float* ws     = (float*)d_ws;
    float* meanT  = ws;                  // 256
    float* rowmin = ws + 256;            // 9216
    float* rowsum = rowmin + S;          // 9216
    float* colmax = rowsum + S;          // 9216
    __hip_bfloat16* A = (__hip_bfloat16*)(colmax + S);   // byte off 111616 (16B aligned)
    __hip_bfloat16* B = A + (size_t)S * C;
    float* out = (float*)d_out;

    k_mean<<<C, 256, 0, stream>>>(gt, meanT);
    k_norm<<<(S * 4) / 256, 256, 0, stream>>>(img, gt, meanT, A, B);
    k_init<<<(S + 255) / 256, 256, 0, stream>>>(rowmin, rowsum, colmax);

    dim3 grid(NT, NT);
    k_gemm<1><<<grid, 256, 0, stream>>>(A, B, rowmin, rowsum, colmax);
    k_gemm<2><<<grid, 256, 0, stream>>>(A, B, rowmin, rowsum, colmax);
    k_gemm<3><<<grid, 256, 0, stream>>>(A, B, rowmin, rowsum, colmax);

    k_final<<<1, 256, 0, stream>>>(colmax, out);
}